// Round 2
// baseline (155.752 us; speedup 1.0000x reference)
//
#include <hip/hip_runtime.h>
#include <stdint.h>

typedef __attribute__((ext_vector_type(8))) short bf16x8;
typedef __attribute__((ext_vector_type(4))) short bf16x4;
typedef __attribute__((ext_vector_type(4))) float f32x4;
typedef unsigned short u16t;

#define DEVINL static __device__ __forceinline__

DEVINL u16t f2bf(float f) {
  union { float f; unsigned u; } v; v.f = f;
  return (u16t)((v.u + 0x7FFFu + ((v.u >> 16) & 1u)) >> 16);  // RNE, inputs finite
}

DEVINL void gload16(const void* g, void* l) {
  __builtin_amdgcn_global_load_lds((const __attribute__((address_space(1))) void*)g,
                                   (__attribute__((address_space(3))) void*)l, 16, 0, 0);
}

// ---------------- fp32 -> bf16 convert ----------------
__global__ __launch_bounds__(256) void cvt_kernel(const float* __restrict__ src,
                                                  u16t* __restrict__ dst, int n) {
  int i = (blockIdx.x * 256 + threadIdx.x) * 8;
  if (i >= n) return;
  float4 a = *(const float4*)(src + i);
  float4 b = *(const float4*)(src + i + 4);
  union { bf16x8 v; u16t u[8]; } o;
  o.u[0] = f2bf(a.x); o.u[1] = f2bf(a.y); o.u[2] = f2bf(a.z); o.u[3] = f2bf(a.w);
  o.u[4] = f2bf(b.x); o.u[5] = f2bf(b.y); o.u[6] = f2bf(b.z); o.u[7] = f2bf(b.w);
  *(bf16x8*)(dst + i) = o.v;
}

// ---------------- bf16 GEMM: C[M,N] = A[M,K] * Bw[N,K]^T + bias ----------------
// M=4096, K=1024 fixed. MODE 0: N=3072 (Wq|Wk|Wv fused): Q,K bf16 out (Q scaled
// 1/8, [token][hid] layout); V written TRANSPOSED as Vt[b][h][d][s] bf16.
// MODE 1: N=1024 (Wo), fp32 out to d_out.
// 128x128 tile, BK=64, 4 waves (2x2), 16x16x32 bf16 MFMA, 4x4 frags/wave.
// LDS rows are 128 B; read-side XOR swizzle slot^=(row&7); global_load_lds keeps
// the LDS destination linear and pre-applies the inverse swizzle on the source.
template <int MODE>
__global__ __launch_bounds__(256, 2)
void gemm_kernel(const u16t* __restrict__ A, const u16t* __restrict__ Bw,
                 const float* __restrict__ bias0, const float* __restrict__ bias1,
                 const float* __restrict__ bias2, void* __restrict__ outp) {
  __shared__ __attribute__((aligned(16))) u16t As[128 * 64];
  __shared__ __attribute__((aligned(16))) u16t Bs[128 * 64];
  const int tid = threadIdx.x;
  const int w = tid >> 6, l = tid & 63;
  const int wm = w >> 1, wn = w & 1;
  const int bm = blockIdx.x, bn = blockIdx.y;
  const int g = l >> 4, r16 = l & 15;
  const int srow = l >> 3, sslot = l & 7;

  f32x4 acc[4][4];
#pragma unroll
  for (int m = 0; m < 4; ++m)
#pragma unroll
    for (int n = 0; n < 4; ++n) acc[m][n] = f32x4{0.f, 0.f, 0.f, 0.f};

  const size_t arow0 = (size_t)bm * 128;
  const size_t brow0 = (size_t)bn * 128;

  for (int kt = 0; kt < 16; ++kt) {
    __syncthreads();
#pragma unroll
    for (int i = 0; i < 4; ++i) {
      const int row = (i * 4 + w) * 8 + srow;               // 0..127 within tile
      const int colA = kt * 64 + ((sslot ^ (row & 7)) * 8); // inverse-swizzled src
      gload16(A + (arow0 + row) * 1024 + colA, (char*)As + (i * 4 + w) * 1024);
      gload16(Bw + (brow0 + row) * 1024 + colA, (char*)Bs + (i * 4 + w) * 1024);
    }
    asm volatile("s_waitcnt vmcnt(0)" ::: "memory");
    __syncthreads();
#pragma unroll
    for (int kk = 0; kk < 2; ++kk) {
      bf16x8 af[4], bfr[4];
#pragma unroll
      for (int m = 0; m < 4; ++m) {
        const int rr = wm * 64 + m * 16 + r16;
        af[m] = *(const bf16x8*)((const char*)As + rr * 128 + (((kk * 4 + g) ^ (rr & 7)) * 16));
      }
#pragma unroll
      for (int n = 0; n < 4; ++n) {
        const int rr = wn * 64 + n * 16 + r16;
        bfr[n] = *(const bf16x8*)((const char*)Bs + rr * 128 + (((kk * 4 + g) ^ (rr & 7)) * 16));
      }
#pragma unroll
      for (int m = 0; m < 4; ++m)
#pragma unroll
        for (int n = 0; n < 4; ++n)
          acc[m][n] = __builtin_amdgcn_mfma_f32_16x16x32_bf16(af[m], bfr[n], acc[m][n], 0, 0, 0);
    }
  }

  if (MODE == 0) {
    const int mat = bn >> 3;  // 0=Q,1=K,2=V
    if (mat == 2) {
      // V: write transposed Vt[b][h][d][s], s contiguous (8B stores)
      u16t* vt = (u16t*)outp + 8388608u;  // after Q(4M) + K(4M) elements
#pragma unroll
      for (int n = 0; n < 4; ++n) {
        const int col = ((bn & 7) * 128) + wn * 64 + n * 16 + r16;  // h*64+d
        const int hh = col >> 6, dd = col & 63;
        const float bv = bias2[col];
#pragma unroll
        for (int m = 0; m < 4; ++m) {
          const int row0 = bm * 128 + wm * 64 + m * 16 + g * 4;  // token
          const int b_ = row0 >> 11, s_ = row0 & 2047;
          union { bf16x4 v; u16t u[4]; } o4;
#pragma unroll
          for (int i = 0; i < 4; ++i) o4.u[i] = f2bf(acc[m][n][i] + bv);
          *(bf16x4*)(vt + ((size_t)(b_ * 16 + hh) * 64 + dd) * 2048 + s_) = o4.v;
        }
      }
    } else {
      const float* bias = (mat == 0) ? bias0 : bias1;
      const float scale = (mat == 0) ? 0.125f : 1.0f;  // fold 1/sqrt(64) into Q
      u16t* o = (u16t*)outp + (size_t)mat * 4194304u;
#pragma unroll
      for (int n = 0; n < 4; ++n) {
        const int col = ((bn & 7) * 128) + wn * 64 + n * 16 + r16;
        const float bv = bias[col];
#pragma unroll
        for (int m = 0; m < 4; ++m) {
          const int row = bm * 128 + wm * 64 + m * 16 + g * 4;
#pragma unroll
          for (int i = 0; i < 4; ++i)
            o[(size_t)(row + i) * 1024 + col] = f2bf((acc[m][n][i] + bv) * scale);
        }
      }
    }
  } else {
    float* o = (float*)outp;
#pragma unroll
    for (int n = 0; n < 4; ++n) {
      const int col = bn * 128 + wn * 64 + n * 16 + r16;
      const float bv = bias0[col];
#pragma unroll
      for (int m = 0; m < 4; ++m) {
        const int row = bm * 128 + wm * 64 + m * 16 + g * 4;
#pragma unroll
        for (int i = 0; i < 4; ++i)
          o[(size_t)(row + i) * 1024 + col] = acc[m][n][i] + bv;
      }
    }
  }
}

// ---------------- flash attention with ALiBi (bidirectional) ----------------
// Q pre-scaled by 1/8. grid = (32 q-tiles, 32 b*h), 256 threads = 4 waves,
// each wave owns 16 q rows. Swapped QK^T: S^T = mfma(K, Q) so P lands in the
// PV B-fragment layout; perm(r)=8*(r>>2)+(r&3) on K A-rows makes the register
// k-order match the K=32 PV fragment. V comes pre-transposed (Vt[b][h][d][s]);
// staged linearly into LDS [64 d][32 keys] with pair-line XOR swizzle
// (pos ^= line&7 within 128B lines), read back as contiguous ds_read_b128.
__global__ __launch_bounds__(256, 2)
void attn_kernel(const u16t* __restrict__ Qb, const u16t* __restrict__ Kb,
                 const u16t* __restrict__ Vtb, const float* __restrict__ slopes,
                 u16t* __restrict__ Ctx) {
  __shared__ __attribute__((aligned(16))) u16t Kl[2048];  // [32 keys][64 d] swizzled
  __shared__ __attribute__((aligned(16))) u16t Vl[2048];  // [64 d][32 keys] swizzled
  const int tid = threadIdx.x;
  const int w = tid >> 6, l = tid & 63;
  const int g = l >> 4, r = l & 15;
  const int qt = blockIdx.x, bh = blockIdx.y;
  const int b = bh >> 4, h = bh & 15;
  const float slope = slopes[h];
  const int q0 = qt * 64 + w * 16;
  const int qpos = q0 + r;
  const size_t base = (size_t)b * 2097152 + (size_t)h * 64;

  const u16t* qrow = Qb + base + (size_t)qpos * 1024;
  const bf16x8 qf0 = *(const bf16x8*)(qrow + g * 8);
  const bf16x8 qf1 = *(const bf16x8*)(qrow + 32 + g * 8);

  const int p0 = 8 * (r >> 2) + (r & 3);  // permuted K-lds row for S^T tile0
  const int p1 = p0 + 4;                  // tile1
  const int ka00 = p0 * 128 + ((g ^ (p0 & 7)) * 16);
  const int ka01 = p0 * 128 + (((4 + g) ^ (p0 & 7)) * 16);
  const int ka10 = p1 * 128 + ((g ^ (p1 & 7)) * 16);
  const int ka11 = p1 * 128 + (((4 + g) ^ (p1 & 7)) * 16);

  // K staging: LDS row = w*8 + l>>3 (64 elem rows), slot = l&7, source slot XOR'd
  const int ks_row = tid >> 3;
  const int ks_col = ((tid & 7) ^ (ks_row & 7)) * 8;
  // V staging: LDS [64 d][32 keys]; line = d>>1 (128B), pos = (d&1)*4+slot.
  // Lane l fills line w*8 + (l>>3), pos l&7. Inverse swizzle: u = pos ^ (line&7).
  const int vu = (l & 7) ^ ((l >> 3) & 7);
  const int v_dsrc = w * 16 + 2 * (l >> 3) + (vu >> 2);
  const int v_col = (vu & 3) * 8;
  // V read (PV A-frag): lane (g,r), db: d = db*16+r, key-slot g.
  const int vb_off = (r >> 1) * 128 + (((((r & 1) << 2) | g) ^ ((r >> 1) & 7)) << 4);

  float mrun = -1e30f, rsum = 0.f;
  f32x4 oc[4];
#pragma unroll
  for (int d = 0; d < 4; ++d) oc[d] = f32x4{0.f, 0.f, 0.f, 0.f};

  const u16t* Krow = Kb + base;
  const u16t* Vrow = Vtb + (size_t)(b * 16 + h) * 131072;  // [64][2048]

  for (int kt = 0; kt < 64; ++kt) {
    __syncthreads();
    gload16(Krow + (size_t)(kt * 32 + ks_row) * 1024 + ks_col, (char*)Kl + w * 1024);
    gload16(Vrow + (size_t)v_dsrc * 2048 + kt * 32 + v_col, (char*)Vl + w * 1024);
    asm volatile("s_waitcnt vmcnt(0)" ::: "memory");
    __syncthreads();

    f32x4 st0 = {0.f, 0.f, 0.f, 0.f}, st1 = {0.f, 0.f, 0.f, 0.f};
    {
      const char* KB = (const char*)Kl;
      bf16x8 a0 = *(const bf16x8*)(KB + ka00);
      bf16x8 a1 = *(const bf16x8*)(KB + ka01);
      bf16x8 a2 = *(const bf16x8*)(KB + ka10);
      bf16x8 a3 = *(const bf16x8*)(KB + ka11);
      st0 = __builtin_amdgcn_mfma_f32_16x16x32_bf16(a0, qf0, st0, 0, 0, 0);
      st0 = __builtin_amdgcn_mfma_f32_16x16x32_bf16(a1, qf1, st0, 0, 0, 0);
      st1 = __builtin_amdgcn_mfma_f32_16x16x32_bf16(a2, qf0, st1, 0, 0, 0);
      st1 = __builtin_amdgcn_mfma_f32_16x16x32_bf16(a3, qf1, st1, 0, 0, 0);
    }
    // st0[i]: key pos kt*32+8g+i ; st1[i]: kt*32+8g+4+i ; query col q = r
    const float kb0 = (float)(kt * 32 + 8 * g - qpos);
    float tm = -1e30f;
#pragma unroll
    for (int i = 0; i < 4; ++i) { st0[i] += slope * (kb0 + i); tm = fmaxf(tm, st0[i]); }
#pragma unroll
    for (int i = 0; i < 4; ++i) { st1[i] += slope * (kb0 + 4 + i); tm = fmaxf(tm, st1[i]); }
    tm = fmaxf(tm, __shfl_xor(tm, 16));
    tm = fmaxf(tm, __shfl_xor(tm, 32));
    const float mn = fmaxf(mrun, tm);
    const float corr = __expf(mrun - mn);
    float ps = 0.f;
    union { bf16x8 v; u16t u[8]; } pb;
#pragma unroll
    for (int i = 0; i < 4; ++i) { float p = __expf(st0[i] - mn); ps += p; pb.u[i] = f2bf(p); }
#pragma unroll
    for (int i = 0; i < 4; ++i) { float p = __expf(st1[i] - mn); ps += p; pb.u[4 + i] = f2bf(p); }
    ps += __shfl_xor(ps, 16);
    ps += __shfl_xor(ps, 32);
    rsum = rsum * corr + ps;
    mrun = mn;
#pragma unroll
    for (int d = 0; d < 4; ++d) {
      oc[d][0] *= corr; oc[d][1] *= corr; oc[d][2] *= corr; oc[d][3] *= corr;
    }

    const char* VB = (const char*)Vl + vb_off;
    bf16x8 v0 = *(const bf16x8*)(VB);
    bf16x8 v1 = *(const bf16x8*)(VB + 1024);
    bf16x8 v2 = *(const bf16x8*)(VB + 2048);
    bf16x8 v3 = *(const bf16x8*)(VB + 3072);
    oc[0] = __builtin_amdgcn_mfma_f32_16x16x32_bf16(v0, pb.v, oc[0], 0, 0, 0);
    oc[1] = __builtin_amdgcn_mfma_f32_16x16x32_bf16(v1, pb.v, oc[1], 0, 0, 0);
    oc[2] = __builtin_amdgcn_mfma_f32_16x16x32_bf16(v2, pb.v, oc[2], 0, 0, 0);
    oc[3] = __builtin_amdgcn_mfma_f32_16x16x32_bf16(v3, pb.v, oc[3], 0, 0, 0);
  }

  const float inv = 1.f / rsum;
  u16t* orow = Ctx + base + (size_t)qpos * 1024;
#pragma unroll
  for (int d = 0; d < 4; ++d) {
    union { bf16x4 v; u16t u[4]; } o4;
#pragma unroll
    for (int i = 0; i < 4; ++i) o4.u[i] = f2bf(oc[d][i] * inv);
    *(bf16x4*)(orow + d * 16 + g * 4) = o4.v;
  }
}

extern "C" void kernel_launch(void* const* d_in, const int* in_sizes, int n_in,
                              void* d_out, int out_size, void* d_ws, size_t ws_size,
                              hipStream_t stream) {
  const float* x = (const float*)d_in[0];
  const float* Wq = (const float*)d_in[1];
  const float* bq = (const float*)d_in[2];
  const float* Wk = (const float*)d_in[3];
  const float* bk = (const float*)d_in[4];
  const float* Wv = (const float*)d_in[5];
  const float* bv = (const float*)d_in[6];
  const float* Wo = (const float*)d_in[7];
  const float* bo = (const float*)d_in[8];
  const float* slopes = (const float*)d_in[9];
  if (ws_size < (size_t)(48u << 20)) return;
  char* ws = (char*)d_ws;
  u16t* x_bf = (u16t*)(ws);                  //  8 MB: x bf16 [4096][1024]
  u16t* wqkv = (u16t*)(ws + (8u << 20));     //  6 MB: Wq|Wk|Wv bf16 [3072][1024]
  u16t* wo_bf = (u16t*)(ws + (14u << 20));   //  2 MB: Wo bf16
  u16t* q_bf = (u16t*)(ws + (16u << 20));    // 24 MB: Q | K | Vt bf16 (Q pre-scaled)
  u16t* ctx_bf = (u16t*)(ws + (40u << 20));  //  8 MB: ctx bf16

  cvt_kernel<<<2048, 256, 0, stream>>>(x, x_bf, 4194304);
  cvt_kernel<<<512, 256, 0, stream>>>(Wq, wqkv, 1048576);
  cvt_kernel<<<512, 256, 0, stream>>>(Wk, wqkv + 1048576, 1048576);
  cvt_kernel<<<512, 256, 0, stream>>>(Wv, wqkv + 2097152, 1048576);
  cvt_kernel<<<512, 256, 0, stream>>>(Wo, wo_bf, 1048576);
  gemm_kernel<0><<<dim3(32, 24), 256, 0, stream>>>(x_bf, wqkv, bq, bk, bv, (void*)q_bf);
  attn_kernel<<<dim3(32, 32), 256, 0, stream>>>(q_bf, q_bf + 4194304, q_bf + 8388608,
                                                slopes, ctx_bf);
  gemm_kernel<1><<<dim3(32, 8), 256, 0, stream>>>(ctx_bf, wo_bf, bo, bo, bo, d_out);
}

// Round 3
// 120.990 us; speedup vs baseline: 1.2873x; 1.2873x over previous
//
#include <hip/hip_runtime.h>
#include <stdint.h>

typedef __attribute__((ext_vector_type(8))) short bf16x8;
typedef __attribute__((ext_vector_type(4))) short bf16x4;
typedef __attribute__((ext_vector_type(4))) float f32x4;
typedef unsigned short u16t;

#define DEVINL static __device__ __forceinline__

DEVINL u16t f2bf(float f) {
  union { float f; unsigned u; } v; v.f = f;
  return (u16t)((v.u + 0x7FFFu + ((v.u >> 16) & 1u)) >> 16);  // RNE, inputs finite
}

DEVINL float exp2_fast(float x) {
  float r; asm("v_exp_f32 %0, %1" : "=v"(r) : "v"(x)); return r;
}
DEVINL unsigned cvt_pk_bf16(float a, float b) {  // lo16=bf16(a), hi16=bf16(b)
  unsigned r; asm("v_cvt_pk_bf16_f32 %0, %1, %2" : "=v"(r) : "v"(a), "v"(b)); return r;
}

DEVINL void gload16(const void* g, void* l) {
  __builtin_amdgcn_global_load_lds((const __attribute__((address_space(1))) void*)g,
                                   (__attribute__((address_space(3))) void*)l, 16, 0, 0);
}

// ---------------- fp32 -> bf16 convert (all 5 tensors, one launch) ----------------
__global__ __launch_bounds__(256)
void cvt5_kernel(const float* __restrict__ x, const float* __restrict__ wq,
                 const float* __restrict__ wk, const float* __restrict__ wv,
                 const float* __restrict__ wo, u16t* __restrict__ x_bf,
                 u16t* __restrict__ wqkv, u16t* __restrict__ wo_bf) {
  const int bid = blockIdx.x;
  const float* src; u16t* dst; int off;
  if (bid < 2048) { src = x; dst = x_bf; off = bid * 2048; }
  else {
    const int j = bid - 2048, sel = j >> 9;
    off = (j & 511) * 2048;
    if (sel == 0)      { src = wq; dst = wqkv; }
    else if (sel == 1) { src = wk; dst = wqkv + 1048576; }
    else if (sel == 2) { src = wv; dst = wqkv + 2097152; }
    else               { src = wo; dst = wo_bf; }
  }
  const int i = off + threadIdx.x * 8;
  float4 a = *(const float4*)(src + i);
  float4 b = *(const float4*)(src + i + 4);
  union { bf16x8 v; u16t u[8]; } o;
  o.u[0] = f2bf(a.x); o.u[1] = f2bf(a.y); o.u[2] = f2bf(a.z); o.u[3] = f2bf(a.w);
  o.u[4] = f2bf(b.x); o.u[5] = f2bf(b.y); o.u[6] = f2bf(b.z); o.u[7] = f2bf(b.w);
  *(bf16x8*)(dst + i) = o.v;
}

// ---------------- bf16 GEMM: C[M,N] = A[M,K] * Bw[N,K]^T + bias ----------------
// M=4096, K=1024. MODE 0: N=3072 (Wq|Wk|Wv): Q scaled by 0.125*log2(e), V written
// transposed as Vt[b][h][d][s]. MODE 1: N=1024 (Wo), fp32 out.
template <int MODE>
__global__ __launch_bounds__(256, 2)
void gemm_kernel(const u16t* __restrict__ A, const u16t* __restrict__ Bw,
                 const float* __restrict__ bias0, const float* __restrict__ bias1,
                 const float* __restrict__ bias2, void* __restrict__ outp) {
  __shared__ __attribute__((aligned(16))) u16t As[128 * 64];
  __shared__ __attribute__((aligned(16))) u16t Bs[128 * 64];
  const int tid = threadIdx.x;
  const int w = tid >> 6, l = tid & 63;
  const int wm = w >> 1, wn = w & 1;
  const int bm = blockIdx.x, bn = blockIdx.y;
  const int g = l >> 4, r16 = l & 15;
  const int srow = l >> 3, sslot = l & 7;

  f32x4 acc[4][4];
#pragma unroll
  for (int m = 0; m < 4; ++m)
#pragma unroll
    for (int n = 0; n < 4; ++n) acc[m][n] = f32x4{0.f, 0.f, 0.f, 0.f};

  const size_t arow0 = (size_t)bm * 128;
  const size_t brow0 = (size_t)bn * 128;

  for (int kt = 0; kt < 16; ++kt) {
    __syncthreads();
#pragma unroll
    for (int i = 0; i < 4; ++i) {
      const int row = (i * 4 + w) * 8 + srow;
      const int colA = kt * 64 + ((sslot ^ (row & 7)) * 8);
      gload16(A + (arow0 + row) * 1024 + colA, (char*)As + (i * 4 + w) * 1024);
      gload16(Bw + (brow0 + row) * 1024 + colA, (char*)Bs + (i * 4 + w) * 1024);
    }
    asm volatile("s_waitcnt vmcnt(0)" ::: "memory");
    __syncthreads();
#pragma unroll
    for (int kk = 0; kk < 2; ++kk) {
      bf16x8 af[4], bfr[4];
#pragma unroll
      for (int m = 0; m < 4; ++m) {
        const int rr = wm * 64 + m * 16 + r16;
        af[m] = *(const bf16x8*)((const char*)As + rr * 128 + (((kk * 4 + g) ^ (rr & 7)) * 16));
      }
#pragma unroll
      for (int n = 0; n < 4; ++n) {
        const int rr = wn * 64 + n * 16 + r16;
        bfr[n] = *(const bf16x8*)((const char*)Bs + rr * 128 + (((kk * 4 + g) ^ (rr & 7)) * 16));
      }
#pragma unroll
      for (int m = 0; m < 4; ++m)
#pragma unroll
        for (int n = 0; n < 4; ++n)
          acc[m][n] = __builtin_amdgcn_mfma_f32_16x16x32_bf16(af[m], bfr[n], acc[m][n], 0, 0, 0);
    }
  }

  if (MODE == 0) {
    const int mat = bn >> 3;  // 0=Q,1=K,2=V
    if (mat == 2) {
      u16t* vt = (u16t*)outp + 8388608u;
#pragma unroll
      for (int n = 0; n < 4; ++n) {
        const int col = ((bn & 7) * 128) + wn * 64 + n * 16 + r16;  // h*64+d
        const int hh = col >> 6, dd = col & 63;
        const float bv = bias2[col];
#pragma unroll
        for (int m = 0; m < 4; ++m) {
          const int row0 = bm * 128 + wm * 64 + m * 16 + g * 4;
          const int b_ = row0 >> 11, s_ = row0 & 2047;
          union { bf16x4 v; u16t u[4]; } o4;
#pragma unroll
          for (int i = 0; i < 4; ++i) o4.u[i] = f2bf(acc[m][n][i] + bv);
          *(bf16x4*)(vt + ((size_t)(b_ * 16 + hh) * 64 + dd) * 2048 + s_) = o4.v;
        }
      }
    } else {
      const float* bias = (mat == 0) ? bias0 : bias1;
      // Q: fold 1/sqrt(64) * log2(e) so attention works in exp2 domain
      const float scale = (mat == 0) ? 0.18033688f : 1.0f;
      u16t* o = (u16t*)outp + (size_t)mat * 4194304u;
#pragma unroll
      for (int n = 0; n < 4; ++n) {
        const int col = ((bn & 7) * 128) + wn * 64 + n * 16 + r16;
        const float bv = bias[col];
#pragma unroll
        for (int m = 0; m < 4; ++m) {
          const int row = bm * 128 + wm * 64 + m * 16 + g * 4;
#pragma unroll
          for (int i = 0; i < 4; ++i)
            o[(size_t)(row + i) * 1024 + col] = f2bf((acc[m][n][i] + bv) * scale);
        }
      }
    }
  } else {
    float* o = (float*)outp;
#pragma unroll
    for (int n = 0; n < 4; ++n) {
      const int col = bn * 128 + wn * 64 + n * 16 + r16;
      const float bv = bias0[col];
#pragma unroll
      for (int m = 0; m < 4; ++m) {
        const int row = bm * 128 + wm * 64 + m * 16 + g * 4;
#pragma unroll
        for (int i = 0; i < 4; ++i)
          o[(size_t)(row + i) * 1024 + col] = acc[m][n][i] + bv;
      }
    }
  }
}

// ---------------- flash attention with ALiBi (bidirectional) ----------------
// exp2 domain: Q pre-scaled by 0.125*log2e. ALiBi -slope*i term cancels in
// softmax; remaining slope2*j folded into QK MFMA C-init (cv) + per-iter mj
// offset. Tiles iterated high->low so the running max is found immediately;
// rescale path (__any(tm>mj)) almost never taken. Row-sum via ones-MFMA.
// KVBLK=64, 2-buffer LDS, 1 barrier/iter, loads in flight across compute.
__global__ __launch_bounds__(256, 2)
void attn_kernel(const u16t* __restrict__ Qb, const u16t* __restrict__ Kb,
                 const u16t* __restrict__ Vtb, const float* __restrict__ slopes,
                 u16t* __restrict__ Ctx) {
  __shared__ __attribute__((aligned(16))) u16t Kl[2][4096];  // [64 keys][64 d] swz
  __shared__ __attribute__((aligned(16))) u16t Vl[2][4096];  // [64 d][64 keys] swz
  const int tid = threadIdx.x;
  const int w = tid >> 6, l = tid & 63;
  const int g = l >> 4, r = l & 15;
  const int qt = blockIdx.x, bh = blockIdx.y;
  const int b = bh >> 4, h = bh & 15;
  const float slope2 = slopes[h] * 1.44269504f;
  const int qpos = qt * 64 + w * 16 + r;
  const size_t base = (size_t)b * 2097152 + (size_t)h * 64;

  const u16t* qrow = Qb + base + (size_t)qpos * 1024;
  const bf16x8 qf0 = *(const bf16x8*)(qrow + g * 8);
  const bf16x8 qf1 = *(const bf16x8*)(qrow + 32 + g * 8);

  // K A-frag offsets: row perm sigma(r)=8*(r>>2)+(r&3) (+{0,4,32,36});
  // K-tile swizzle mask (row&3)^((row>>1)&4) -> every 8-lane phase is a slot perm.
  const int sig = 8 * (r >> 2) + (r & 3);
  const int toffs[4] = {0, 4, 32, 36};
  int koff[4][2], voff[4][2];
#pragma unroll
  for (int t = 0; t < 4; ++t) {
    const int row = toffs[t] + sig;
    const int mk = (row & 3) ^ ((row >> 1) & 4);
#pragma unroll
    for (int hh = 0; hh < 2; ++hh) koff[t][hh] = row * 128 + (((hh * 4 + g) ^ mk) * 16);
  }
#pragma unroll
  for (int db = 0; db < 4; ++db) {
    const int row = 16 * db + r;  // V-tile: classic (row&7) swizzle
#pragma unroll
    for (int hh = 0; hh < 2; ++hh) voff[db][hh] = row * 128 + (((hh * 4 + g) ^ (row & 7)) * 16);
  }

  // staging source geometry (pass p=0,1; LDS dest linear, source pre-swizzled)
  int k_row[2], k_u[2], v_u[2];
#pragma unroll
  for (int p = 0; p < 2; ++p) {
    const int line = p * 32 + w * 8 + (l >> 3);
    k_row[p] = line;
    k_u[p] = ((l & 7) ^ ((line & 3) ^ ((line >> 1) & 4))) * 8;
    v_u[p] = ((l & 7) ^ (line & 7)) * 8;
  }

  // ALiBi C-init frags: cv[t][i] = slope2 * (local_j) for st[t][i] <-> key toff+8g+i
  f32x4 cv[4];
#pragma unroll
  for (int t = 0; t < 4; ++t)
#pragma unroll
    for (int i = 0; i < 4; ++i) cv[t][i] = slope2 * (float)(toffs[t] + 8 * g + i);

  const float d64 = slope2 * 64.f;
  float mj = -3.0e38f;
  f32x4 oc[4], sacc;
#pragma unroll
  for (int d = 0; d < 4; ++d) oc[d] = f32x4{0.f, 0.f, 0.f, 0.f};
  sacc = f32x4{0.f, 0.f, 0.f, 0.f};
  union { bf16x8 v; u16t u[8]; } ones;
#pragma unroll
  for (int i = 0; i < 8; ++i) ones.u[i] = 0x3F80;  // 1.0 bf16

  const u16t* Krow = Kb + base;
  const u16t* Vrow = Vtb + (size_t)(b * 16 + h) * 131072;  // [64][2048]

  // prologue: stage tile 31 into buf 0
#pragma unroll
  for (int p = 0; p < 2; ++p) {
    gload16(Krow + (size_t)(31 * 64 + k_row[p]) * 1024 + k_u[p],
            (char*)Kl + p * 4096 + w * 1024);
    gload16(Vrow + (size_t)k_row[p] * 2048 + 31 * 64 + v_u[p],
            (char*)Vl + p * 4096 + w * 1024);
  }

  for (int it = 0; it < 32; ++it) {
    const int kt = 31 - it;
    const int buf = it & 1;
    __syncthreads();  // drains my vmcnt; barrier => all waves' tile-kt data in LDS
    if (it) mj += d64;  // local-bias coordinate shift (kt decreased by 1)
    if (it + 1 < 32) {  // issue next-tile loads; they fly across this compute
      const int nb = buf ^ 1, nkt = kt - 1;
#pragma unroll
      for (int p = 0; p < 2; ++p) {
        gload16(Krow + (size_t)(nkt * 64 + k_row[p]) * 1024 + k_u[p],
                (char*)Kl + nb * 8192 + p * 4096 + w * 1024);
        gload16(Vrow + (size_t)k_row[p] * 2048 + nkt * 64 + v_u[p],
                (char*)Vl + nb * 8192 + p * 4096 + w * 1024);
      }
    }
    const char* KB = (const char*)Kl + buf * 8192;
    const char* VB = (const char*)Vl + buf * 8192;

    f32x4 st[4];
#pragma unroll
    for (int t = 0; t < 4; ++t) {
      st[t] = __builtin_amdgcn_mfma_f32_16x16x32_bf16(
          *(const bf16x8*)(KB + koff[t][0]), qf0, cv[t], 0, 0, 0);
      st[t] = __builtin_amdgcn_mfma_f32_16x16x32_bf16(
          *(const bf16x8*)(KB + koff[t][1]), qf1, st[t], 0, 0, 0);
    }

    float tm = fmaxf(fmaxf(st[0][0], st[0][1]), fmaxf(st[0][2], st[0][3]));
    tm = fmaxf(tm, fmaxf(fmaxf(st[1][0], st[1][1]), fmaxf(st[1][2], st[1][3])));
    tm = fmaxf(tm, fmaxf(fmaxf(st[2][0], st[2][1]), fmaxf(st[2][2], st[2][3])));
    tm = fmaxf(tm, fmaxf(fmaxf(st[3][0], st[3][1]), fmaxf(st[3][2], st[3][3])));
    if (__any(tm > mj)) {  // rare: reverse order => max found in first tiles
      float tr = fmaxf(tm, __shfl_xor(tm, 16));
      tr = fmaxf(tr, __shfl_xor(tr, 32));
      const float mn = fmaxf(mj, tr);
      const float corr = exp2_fast(mj - mn);
#pragma unroll
      for (int d = 0; d < 4; ++d) {
        oc[d][0] *= corr; oc[d][1] *= corr; oc[d][2] *= corr; oc[d][3] *= corr;
      }
      sacc[0] *= corr; sacc[1] *= corr; sacc[2] *= corr; sacc[3] *= corr;
      mj = mn;
    }

    float pe[16];
#pragma unroll
    for (int t = 0; t < 4; ++t)
#pragma unroll
      for (int i = 0; i < 4; ++i) pe[t * 4 + i] = exp2_fast(st[t][i] - mj);
    union { bf16x8 v; unsigned q[4]; } pb0, pb1;
#pragma unroll
    for (int j = 0; j < 4; ++j) {
      pb0.q[j] = cvt_pk_bf16(pe[j * 2], pe[j * 2 + 1]);
      pb1.q[j] = cvt_pk_bf16(pe[8 + j * 2], pe[8 + j * 2 + 1]);
    }

#pragma unroll
    for (int db = 0; db < 4; ++db) {
      oc[db] = __builtin_amdgcn_mfma_f32_16x16x32_bf16(
          *(const bf16x8*)(VB + voff[db][0]), pb0.v, oc[db], 0, 0, 0);
      oc[db] = __builtin_amdgcn_mfma_f32_16x16x32_bf16(
          *(const bf16x8*)(VB + voff[db][1]), pb1.v, oc[db], 0, 0, 0);
    }
    sacc = __builtin_amdgcn_mfma_f32_16x16x32_bf16(ones.v, pb0.v, sacc, 0, 0, 0);
    sacc = __builtin_amdgcn_mfma_f32_16x16x32_bf16(ones.v, pb1.v, sacc, 0, 0, 0);
  }

  const float inv = 1.0f / sacc[0];
  u16t* orow = Ctx + base + (size_t)qpos * 1024;
#pragma unroll
  for (int d = 0; d < 4; ++d) {
    union { bf16x4 v; u16t u[4]; } o4;
#pragma unroll
    for (int i = 0; i < 4; ++i) o4.u[i] = f2bf(oc[d][i] * inv);
    *(bf16x4*)(orow + d * 16 + g * 4) = o4.v;
  }
}

extern "C" void kernel_launch(void* const* d_in, const int* in_sizes, int n_in,
                              void* d_out, int out_size, void* d_ws, size_t ws_size,
                              hipStream_t stream) {
  const float* x = (const float*)d_in[0];
  const float* Wq = (const float*)d_in[1];
  const float* bq = (const float*)d_in[2];
  const float* Wk = (const float*)d_in[3];
  const float* bk = (const float*)d_in[4];
  const float* Wv = (const float*)d_in[5];
  const float* bv = (const float*)d_in[6];
  const float* Wo = (const float*)d_in[7];
  const float* bo = (const float*)d_in[8];
  const float* slopes = (const float*)d_in[9];
  if (ws_size < (size_t)(48u << 20)) return;
  char* ws = (char*)d_ws;
  u16t* x_bf = (u16t*)(ws);                  //  8 MB: x bf16 [4096][1024]
  u16t* wqkv = (u16t*)(ws + (8u << 20));     //  6 MB: Wq|Wk|Wv bf16
  u16t* wo_bf = (u16t*)(ws + (14u << 20));   //  2 MB: Wo bf16
  u16t* q_bf = (u16t*)(ws + (16u << 20));    // 24 MB: Q | K | Vt bf16
  u16t* ctx_bf = (u16t*)(ws + (40u << 20));  //  8 MB: ctx bf16

  cvt5_kernel<<<4096, 256, 0, stream>>>(x, Wq, Wk, Wv, Wo, x_bf, wqkv, wo_bf);
  gemm_kernel<0><<<dim3(32, 24), 256, 0, stream>>>(x_bf, wqkv, bq, bk, bv, (void*)q_bf);
  attn_kernel<<<dim3(32, 32), 256, 0, stream>>>(q_bf, q_bf + 4194304, q_bf + 8388608,
                                                slopes, ctx_bf);
  gemm_kernel<1><<<dim3(32, 8), 256, 0, stream>>>(ctx_bf, wo_bf, bo, bo, bo, d_out);
}